// Round 4
// baseline (67.961 us; speedup 1.0000x reference)
//
#include <hip/hip_runtime.h>

// IndirectLearningDPD: GMP basis (64 cols) + complex matmul, factored into an
// 8-tap complex stencil:
//
// y[n] = sum_{d=0..3} x[n-d] * C_d(n-d), where for m = n-d:
//   C_d(m) = c[0+d] + c[4+d]*a2[m] + c[8+d]*a4[m] + c[12+d]*a6[m]
//          + c[16+d]*a2[m-1] + c[20+d]*a2[m-2]
//          + c[24+d]*a4[m-1] + c[28+d]*a4[m-2]
//          + c[32+d]*a6[m-1] + c[36+d]*a6[m-2]
//          + c[40+d]*a2[m+1] + c[44+d]*a2[m+2]
//          + c[48+d]*a4[m+1] + c[52+d]*a4[m+2]
//          + c[56+d]*a6[m+1] + c[60+d]*a6[m+2]
// a2 = |x|^2 (even powers -> no sqrt); out-of-range positions are exact
// zeros (zero-staged halo), matching the reference's delay padding.
//
// ABI (verified R3): inputs are 4 fp32 arrays; output is PLANAR complex64 —
// out[0:N] = real, out[N:2N] = imag; out_size = 2N floats.
//
// R4: 4 outputs/thread, float4 global I/O + float4 LDS staging, window of 11
// positions shared across the 4 outputs. Device time target ~4 us; the bench
// dur_us floor also contains ~42 us of harness d_ws re-poison (fillBuffer
// dispatches seen in rocprof) + launch overhead, which we cannot touch.

constexpr int BLOCK  = 256;
constexpr int VPT    = 4;                    // outputs per thread
constexpr int SAMP   = BLOCK * VPT;          // 1024 samples per block
constexpr int HALO_L = 8;                    // need 5; 8 keeps float4 alignment
constexpr int HALO_R = 4;                    // need 2; 4 keeps float4 alignment
constexpr int TILE   = SAMP + HALO_L + HALO_R;   // 1036 floats
constexpr int TILE4  = TILE / 4;                 // 259 float4

__global__ __launch_bounds__(BLOCK) void dpd_gmp_kernel(
    const float* __restrict__ xr, const float* __restrict__ xi,
    const float* __restrict__ cr, const float* __restrict__ ci,
    float* __restrict__ out, int N, int out_size)
{
    __shared__ __align__(16) float sxr[TILE];
    __shared__ __align__(16) float sxi[TILE];

    const int tid  = threadIdx.x;
    const int base = blockIdx.x * SAMP;

    // ---- Stage window m in [base-8, base+1028) into LDS ----
    const bool interior = (base >= HALO_L) && (base + SAMP + HALO_R <= N);
    if (interior) {
        // fast path: everything in range, float4 loads/stores
        const float4* xr4 = reinterpret_cast<const float4*>(xr + base - HALO_L);
        const float4* xi4 = reinterpret_cast<const float4*>(xi + base - HALO_L);
        float4* sr4 = reinterpret_cast<float4*>(sxr);
        float4* si4 = reinterpret_cast<float4*>(sxi);
        for (int f = tid; f < TILE4; f += BLOCK) {
            sr4[f] = xr4[f];
            si4[f] = xi4[f];
        }
    } else {
        // edge blocks (first/last): per-element, zero-pad out of range
        for (int k = tid; k < TILE; k += BLOCK) {
            int m = base - HALO_L + k;
            bool ok = (m >= 0) && (m < N);
            sxr[k] = ok ? xr[m] : 0.0f;
            sxi[k] = ok ? xi[m] : 0.0f;
        }
    }
    __syncthreads();

    // ---- Window registers: j in [0,11) maps m = n0-5+j (LDS idx l0+j) ----
    const int n0 = base + tid * VPT;
    const int l0 = tid * VPT + HALO_L - 5;   // = tid*4 + 3

    float wr[11], wi[11], p2[11], p4[11], p6[11];
#pragma unroll
    for (int j = 0; j < 11; ++j) {
        wr[j] = sxr[l0 + j];
        wi[j] = sxi[l0 + j];
        float s = wr[j] * wr[j] + wi[j] * wi[j];
        p2[j] = s;
        p4[j] = s * s;
        p6[j] = p4[j] * s;
    }

    float yr[VPT], yi[VPT];
#pragma unroll
    for (int o = 0; o < VPT; ++o) { yr[o] = 0.0f; yi[o] = 0.0f; }

#pragma unroll
    for (int o = 0; o < VPT; ++o) {
#pragma unroll
        for (int d = 0; d < 4; ++d) {
            const int i = 5 + o - d;   // window index of m = n0+o-d

            float Cr = cr[0 + d];
            float Ci = ci[0 + d];
            Cr = fmaf(cr[ 4 + d], p2[i],     Cr);  Ci = fmaf(ci[ 4 + d], p2[i],     Ci);
            Cr = fmaf(cr[ 8 + d], p4[i],     Cr);  Ci = fmaf(ci[ 8 + d], p4[i],     Ci);
            Cr = fmaf(cr[12 + d], p6[i],     Cr);  Ci = fmaf(ci[12 + d], p6[i],     Ci);
            Cr = fmaf(cr[16 + d], p2[i - 1], Cr);  Ci = fmaf(ci[16 + d], p2[i - 1], Ci);
            Cr = fmaf(cr[20 + d], p2[i - 2], Cr);  Ci = fmaf(ci[20 + d], p2[i - 2], Ci);
            Cr = fmaf(cr[24 + d], p4[i - 1], Cr);  Ci = fmaf(ci[24 + d], p4[i - 1], Ci);
            Cr = fmaf(cr[28 + d], p4[i - 2], Cr);  Ci = fmaf(ci[28 + d], p4[i - 2], Ci);
            Cr = fmaf(cr[32 + d], p6[i - 1], Cr);  Ci = fmaf(ci[32 + d], p6[i - 1], Ci);
            Cr = fmaf(cr[36 + d], p6[i - 2], Cr);  Ci = fmaf(ci[36 + d], p6[i - 2], Ci);
            Cr = fmaf(cr[40 + d], p2[i + 1], Cr);  Ci = fmaf(ci[40 + d], p2[i + 1], Ci);
            Cr = fmaf(cr[44 + d], p2[i + 2], Cr);  Ci = fmaf(ci[44 + d], p2[i + 2], Ci);
            Cr = fmaf(cr[48 + d], p4[i + 1], Cr);  Ci = fmaf(ci[48 + d], p4[i + 1], Ci);
            Cr = fmaf(cr[52 + d], p4[i + 2], Cr);  Ci = fmaf(ci[52 + d], p4[i + 2], Ci);
            Cr = fmaf(cr[56 + d], p6[i + 1], Cr);  Ci = fmaf(ci[56 + d], p6[i + 1], Ci);
            Cr = fmaf(cr[60 + d], p6[i + 2], Cr);  Ci = fmaf(ci[60 + d], p6[i + 2], Ci);

            // y[o] += x[n0+o-d] * C_d  (complex MAC; zero-staged x kills
            // out-of-range columns incl. the order-1 term — matches ref pad)
            yr[o] = fmaf(wr[i],  Cr, yr[o]);
            yr[o] = fmaf(-wi[i], Ci, yr[o]);
            yi[o] = fmaf(wr[i],  Ci, yi[o]);
            yi[o] = fmaf(wi[i],  Cr, yi[o]);
        }
    }

    // ---- PLANAR store: out[0:N] = real, out[N:2N] = imag ----
    if (n0 + VPT <= N && N + n0 + VPT <= out_size) {
        // fast path: n0 and N are multiples of 4 -> 16B-aligned float4 stores
        *reinterpret_cast<float4*>(out + n0)     = make_float4(yr[0], yr[1], yr[2], yr[3]);
        *reinterpret_cast<float4*>(out + N + n0) = make_float4(yi[0], yi[1], yi[2], yi[3]);
    } else {
#pragma unroll
        for (int o = 0; o < VPT; ++o) {
            int n = n0 + o;
            if (n < N) {
                if (n < out_size)     out[n]     = yr[o];
                if (N + n < out_size) out[N + n] = yi[o];
            }
        }
    }
}

extern "C" void kernel_launch(void* const* d_in, const int* in_sizes, int n_in,
                              void* d_out, int out_size, void* d_ws, size_t ws_size,
                              hipStream_t stream) {
    const float* xr = (const float*)d_in[0];
    const float* xi = (const float*)d_in[1];
    const float* cr = (const float*)d_in[2];
    const float* ci = (const float*)d_in[3];
    float* out = (float*)d_out;

    const int N = in_sizes[0];  // B*S flattened signal length (524288)
    const int grid = (N + SAMP - 1) / SAMP;
    dpd_gmp_kernel<<<grid, BLOCK, 0, stream>>>(xr, xi, cr, ci, out, N, out_size);
}

// Round 5
// 64.129 us; speedup vs baseline: 1.0597x; 1.0597x over previous
//
#include <hip/hip_runtime.h>

// IndirectLearningDPD: GMP basis + complex matmul, factored into an 8-tap
// complex stencil.
//
// y[n] = sum_{d=0..3} x[n-d] * C_d(n-d), where for m = n-d:
//   C_d(m) = c[0+d]            (order 1, r = 1)
//          + c[4+d]*a2[m]  + c[8+d]*a4[m]  + c[12+d]*a6[m]      (main, orders 3/5/7)
//          + c[16+d]*a2[m-1] + c[20+d]*a2[m-2]                  (lag,  order 3)
//          + c[24+d]*a4[m-1] + c[28+d]*a4[m-2]                  (lag,  order 5)
//          + c[32+d]*a6[m-1] + c[36+d]*a6[m-2]                  (lag,  order 7)
//          + c[40+d]*a2[m+1] + c[44+d]*a2[m+2]                  (lead, order 3)
//          + c[48+d]*a4[m+1] + c[52+d]*a4[m+2]                  (lead, order 5)
//          + c[56+d]*a6[m+1] + c[60+d]*a6[m+2]                  (lead, order 7)
// with a2 = |x|^2 (even powers only -> no sqrt) and all out-of-range
// positions contributing exact zeros (matches the reference's zero padding).
//
// ABI (verified R3): output is PLANAR complex64 — out[0:N] = real,
// out[N:2N] = imag; out_size = 2N floats.
//
// R5 = exact revert to the R3 kernel (measured 63.7 us) as an A/B noise
// test. R4's VPT=4 rewrite measured +4.3 us, same magnitude as the
// run-to-run spread of the harness's ~41 us / 268 MB d_ws re-poison
// (fillBufferAligned in rocprof) that dominates dur_us. Kernel device
// time is ~3 us by arithmetic (8.6 MB traffic @ 6.5 TB/s + 7.1e7 FMA);
// if this repeat lands in the same 62-69 us band, the bench floor is
// harness-structural and the kernel is at its roofline.

constexpr int BLOCK  = 256;
constexpr int HALO_L = 5;  // need m down to n-3-2
constexpr int HALO_R = 2;  // need m up to n+2
constexpr int TILE   = BLOCK + HALO_L + HALO_R;  // 263

__global__ __launch_bounds__(BLOCK) void dpd_gmp_kernel(
    const float* __restrict__ xr, const float* __restrict__ xi,
    const float* __restrict__ cr, const float* __restrict__ ci,
    float* __restrict__ out, int N, int out_size)
{
    __shared__ float sxr[TILE];
    __shared__ float sxi[TILE];

    const int tid  = threadIdx.x;
    const int base = blockIdx.x * BLOCK;

    // Stage window m in [base-5, base+257] into LDS; zero-pad out of range.
    for (int k = tid; k < TILE; k += BLOCK) {
        int m = base - HALO_L + k;
        bool ok = (m >= 0) && (m < N);
        sxr[k] = ok ? xr[m] : 0.0f;
        sxi[k] = ok ? xi[m] : 0.0f;
    }
    __syncthreads();

    const int n = base + tid;

    // Window registers: w in [0,8) maps to m = n-5+w (LDS index tid+w).
    float wr[8], wi[8], p2[8], p4[8], p6[8];
#pragma unroll
    for (int w = 0; w < 8; ++w) {
        wr[w] = sxr[tid + w];
        wi[w] = sxi[tid + w];
        float s = wr[w] * wr[w] + wi[w] * wi[w];
        p2[w] = s;
        p4[w] = s * s;
        p6[w] = p4[w] * s;
    }

    float yr = 0.0f, yi = 0.0f;
#pragma unroll
    for (int d = 0; d < 4; ++d) {
        const int i = HALO_L - d;  // window index of m = n-d

        float Cr = cr[0 + d];
        float Ci = ci[0 + d];
        Cr = fmaf(cr[ 4 + d], p2[i],     Cr);  Ci = fmaf(ci[ 4 + d], p2[i],     Ci);
        Cr = fmaf(cr[ 8 + d], p4[i],     Cr);  Ci = fmaf(ci[ 8 + d], p4[i],     Ci);
        Cr = fmaf(cr[12 + d], p6[i],     Cr);  Ci = fmaf(ci[12 + d], p6[i],     Ci);
        Cr = fmaf(cr[16 + d], p2[i - 1], Cr);  Ci = fmaf(ci[16 + d], p2[i - 1], Ci);
        Cr = fmaf(cr[20 + d], p2[i - 2], Cr);  Ci = fmaf(ci[20 + d], p2[i - 2], Ci);
        Cr = fmaf(cr[24 + d], p4[i - 1], Cr);  Ci = fmaf(ci[24 + d], p4[i - 1], Ci);
        Cr = fmaf(cr[28 + d], p4[i - 2], Cr);  Ci = fmaf(ci[28 + d], p4[i - 2], Ci);
        Cr = fmaf(cr[32 + d], p6[i - 1], Cr);  Ci = fmaf(ci[32 + d], p6[i - 1], Ci);
        Cr = fmaf(cr[36 + d], p6[i - 2], Cr);  Ci = fmaf(ci[36 + d], p6[i - 2], Ci);
        Cr = fmaf(cr[40 + d], p2[i + 1], Cr);  Ci = fmaf(ci[40 + d], p2[i + 1], Ci);
        Cr = fmaf(cr[44 + d], p2[i + 2], Cr);  Ci = fmaf(ci[44 + d], p2[i + 2], Ci);
        Cr = fmaf(cr[48 + d], p4[i + 1], Cr);  Ci = fmaf(ci[48 + d], p4[i + 1], Ci);
        Cr = fmaf(cr[52 + d], p4[i + 2], Cr);  Ci = fmaf(ci[52 + d], p4[i + 2], Ci);
        Cr = fmaf(cr[56 + d], p6[i + 1], Cr);  Ci = fmaf(ci[56 + d], p6[i + 1], Ci);
        Cr = fmaf(cr[60 + d], p6[i + 2], Cr);  Ci = fmaf(ci[60 + d], p6[i + 2], Ci);

        // y += x[n-d] * C_d   (complex multiply-accumulate).
        // x[n-d] is zero-staged for n-d < 0, which kills the whole column
        // including the order-1 constant term — matches reference delay pad.
        yr = fmaf(wr[i],  Cr, yr);
        yr = fmaf(-wi[i], Ci, yr);
        yi = fmaf(wr[i],  Ci, yi);
        yi = fmaf(wi[i],  Cr, yi);
    }

    // PLANAR complex64 output: out[0:N] = real, out[N:2N] = imag.
    // Both streams fully coalesced. Guards keep any ABI surprise non-fatal.
    if (n < N) {
        if (n < out_size)     out[n]     = yr;
        if (N + n < out_size) out[N + n] = yi;
    }
}

extern "C" void kernel_launch(void* const* d_in, const int* in_sizes, int n_in,
                              void* d_out, int out_size, void* d_ws, size_t ws_size,
                              hipStream_t stream) {
    const float* xr = (const float*)d_in[0];
    const float* xi = (const float*)d_in[1];
    const float* cr = (const float*)d_in[2];
    const float* ci = (const float*)d_in[3];
    float* out = (float*)d_out;

    const int N = in_sizes[0];  // B*S flattened signal length
    const int grid = (N + BLOCK - 1) / BLOCK;
    dpd_gmp_kernel<<<grid, BLOCK, 0, stream>>>(xr, xi, cr, ci, out, N, out_size);
}